// Round 9
// baseline (398.826 us; speedup 1.0000x reference)
//
#include <hip/hip_runtime.h>
#include <hip/hip_bf16.h>

// Problem constants (fixed by the reference)
#define CS     128
#define EDIM   256
#define NBATCH 2
#define TLEN   8192
#define NCHUNK 64
#define LEXT   1024
#define KSEL   7

typedef __attribute__((ext_vector_type(8))) short   short8;   // 8 bf16 = 4 VGPR (MFMA A/B frag)
typedef __attribute__((ext_vector_type(4))) float   floatx4;  // MFMA C/D frag

__device__ inline short bf16_of(float f) {
    __hip_bfloat16 h = __float2bfloat16(f);
    return *(short*)&h;
}
__device__ inline float f_of_bf16(short s) {
    __hip_bfloat16 h = *(__hip_bfloat16*)&s;
    return __bfloat162float(h);
}

// async global->LDS, 16B per lane; LDS dest = wave-uniform base + lane*16
__device__ inline void gl_lds16(const void* g, void* l) {
    __builtin_amdgcn_global_load_lds(
        (const __attribute__((address_space(1))) unsigned int*)g,
        (__attribute__((address_space(3))) unsigned int*)l, 16, 0, 0);
}

// ---------------------------------------------------------------------------
// Stage A1: normalize rows, split to bf16 hi/lo (for scores). One wave/row.
// ---------------------------------------------------------------------------
__global__ __launch_bounds__(256) void normsplit_kernel(const float* __restrict__ x,
                                                        short* __restrict__ cn_hi,
                                                        short* __restrict__ cn_lo) {
    int row  = blockIdx.x * 4 + (threadIdx.x >> 6);
    int lane = threadIdx.x & 63;
    const float4 v = ((const float4*)(x + (size_t)row * EDIM))[lane];
    float s = v.x * v.x + v.y * v.y + v.z * v.z + v.w * v.w;
#pragma unroll
    for (int off = 1; off < 64; off <<= 1) s += __shfl_xor(s, off);
    float r = 1.0f / (sqrtf(s) + 1e-6f);

    float c[4] = {v.x * r, v.y * r, v.z * r, v.w * r};
    short hs[4], ls[4];
#pragma unroll
    for (int q = 0; q < 4; ++q) {
        hs[q] = bf16_of(c[q]);
        ls[q] = bf16_of(c[q] - f_of_bf16(hs[q]));
    }
    size_t o = (size_t)row * EDIM + lane * 4;
    *(short4*)(cn_hi + o) = make_short4(hs[0], hs[1], hs[2], hs[3]);
    *(short4*)(cn_lo + o) = make_short4(ls[0], ls[1], ls[2], ls[3]);
}

// ---------------------------------------------------------------------------
// Stage A2: down_proj -> bf16 (single-pass: out GEMM needs hi only)
// ---------------------------------------------------------------------------
__global__ __launch_bounds__(256) void dp_split_kernel(const float* __restrict__ dp,
                                                       short* __restrict__ dph) {
    int idx = (blockIdx.x * 256 + threadIdx.x) * 4;
    float4 v = *(const float4*)(dp + idx);
    *(short4*)(dph + idx) = make_short4(bf16_of(v.x), bf16_of(v.y), bf16_of(v.z), bf16_of(v.w));
}

// ---------------------------------------------------------------------------
// Stage A3: transpose x to [b][e][t], bf16 (hi only, for out B-operand)
// ---------------------------------------------------------------------------
__global__ __launch_bounds__(256) void xt_split_kernel(const float* __restrict__ x,
                                                       short* __restrict__ xth) {
    __shared__ float tile[64][68];
    const int e0 = blockIdx.x * 64, t0 = blockIdx.y * 64, b = blockIdx.z;
    const int tid = threadIdx.x;
    const int cr = tid >> 4, cc = (tid & 15) * 4;
#pragma unroll
    for (int p = 0; p < 4; ++p) {
        int r = cr + p * 16;
        float4 v = *(const float4*)(x + ((size_t)(b * TLEN + t0 + r)) * EDIM + e0 + cc);
        *(float4*)&tile[r][cc] = v;
    }
    __syncthreads();
    const int e = tid >> 2, toff = (tid & 3) * 16;
    short hs[16];
#pragma unroll
    for (int q = 0; q < 16; ++q) hs[q] = bf16_of(tile[toff + q][e]);
    size_t o = ((size_t)(b * EDIM + e0 + e)) * TLEN + t0 + toff;
#pragma unroll
    for (int q4 = 0; q4 < 4; ++q4)
        *(short4*)(xth + o + q4 * 4) = make_short4(hs[q4*4], hs[q4*4+1], hs[q4*4+2], hs[q4*4+3]);
}

// ---------------------------------------------------------------------------
// Stage B v6: pair-per-block (r3 grid: 4032 blocks, 256 thr, 4 blocks/CU)
// with restructured K-loop: ONLY B (j-chunk hi+lo) goes through LDS
// (16 KB/kstep, double-buffered = 32 KB -> occupancy unchanged), A frags are
// register-direct global loads prefetched one kstep ahead. One barrier per
// kstep (was 2). Issue order: stage B(k+1) -> load A(k+1) -> compute(k) ->
// barrier, so A(k) resolves at vmcnt(12) leaving next-kstep loads in flight
// and the barrier drain overlaps full compute. Each wave: rows w*32..+31,
// all 128 cols (acc[2][8]). MFMA per-element sequence identical to r3
// (ks asc; hh,hl,lh) -> sims bit-identical -> selection unchanged.
// ---------------------------------------------------------------------------
__global__ __launch_bounds__(256, 4) void scores_mfma(const short* __restrict__ cn_hi,
                                                      const short* __restrict__ cn_lo,
                                                      float* __restrict__ scores) {
    __shared__ short  Bs[2][2][128 * 32];   // [buf][hi/lo][row*32+k] = 32 KB
    __shared__ double sred[4];

    const int p = blockIdx.x, b = blockIdx.y;
    int i = (int)((1.0f + sqrtf(1.0f + 8.0f * (float)p)) * 0.5f);
    while (i * (i - 1) / 2 > p) --i;
    while (i * (i + 1) / 2 <= p) ++i;
    const int j = p - i * (i - 1) / 2;

    const int tid  = threadIdx.x;
    const int w    = tid >> 6, lane = tid & 63;
    const int quad = lane >> 4, l15 = lane & 15;
    const int rr   = lane >> 2, c16 = (lane & 3) * 8;

    // B staging role: waves 0,1 -> hi rows (w&1)*64..+63; waves 2,3 -> lo
    const short* barr  = (w >= 2) ? cn_lo : cn_hi;
    const int    brow0 = (w & 1) * 64;
    const short* bbase = barr + ((size_t)b * TLEN + (size_t)j * CS + brow0) * EDIM + c16;
    const int    bhl   = w >> 1;

    // A compute rows: wave w owns rows w*32 + rt*16 + l15
    const size_t abase = ((size_t)b * TLEN + (size_t)i * CS + w * 32) * EDIM;

    floatx4 acc[2][8];
#pragma unroll
    for (int rt = 0; rt < 2; ++rt)
#pragma unroll
        for (int ct = 0; ct < 8; ++ct) acc[rt][ct] = (floatx4){0.f, 0.f, 0.f, 0.f};

    short8 ah[2], al[2], ah2[2], al2[2];

    // prologue: stage B(0) into buf 0; load A(0)
#pragma unroll
    for (int t = 0; t < 4; ++t)
        gl_lds16(bbase + (size_t)(t * 16 + rr) * EDIM, &Bs[0][bhl][(brow0 + t * 16) * 32]);
#pragma unroll
    for (int rt = 0; rt < 2; ++rt) {
        size_t off = abase + (size_t)(rt * 16 + l15) * EDIM + quad * 8;
        ah[rt] = *(const short8*)(cn_hi + off);
        al[rt] = *(const short8*)(cn_lo + off);
    }
    __syncthreads();

    int buf = 0;
#pragma unroll
    for (int ks = 0; ks < 8; ++ks) {
        if (ks < 7) {
            // stage B(k+1) into other buffer (overlaps compute below)
#pragma unroll
            for (int t = 0; t < 4; ++t)
                gl_lds16(bbase + (size_t)(t * 16 + rr) * EDIM + (ks + 1) * 32,
                         &Bs[buf ^ 1][bhl][(brow0 + t * 16) * 32]);
            // prefetch A(k+1) into registers
#pragma unroll
            for (int rt = 0; rt < 2; ++rt) {
                size_t off = abase + (size_t)(rt * 16 + l15) * EDIM + (ks + 1) * 32 + quad * 8;
                ah2[rt] = *(const short8*)(cn_hi + off);
                al2[rt] = *(const short8*)(cn_lo + off);
            }
        }
        // compute(k) on current buffer
#pragma unroll
        for (int ct = 0; ct < 8; ++ct) {
            const short* pb = &Bs[buf][0][(ct * 16 + l15) * 32 + quad * 8];
            short8 bh = *(const short8*)pb;
            short8 bl = *(const short8*)(pb + 128 * 32);
#pragma unroll
            for (int rt = 0; rt < 2; ++rt) {
                acc[rt][ct] = __builtin_amdgcn_mfma_f32_16x16x32_bf16(ah[rt], bh, acc[rt][ct], 0, 0, 0);
                acc[rt][ct] = __builtin_amdgcn_mfma_f32_16x16x32_bf16(ah[rt], bl, acc[rt][ct], 0, 0, 0);
                acc[rt][ct] = __builtin_amdgcn_mfma_f32_16x16x32_bf16(al[rt], bh, acc[rt][ct], 0, 0, 0);
            }
        }
        __syncthreads();   // B(k+1) staged + buf free; drain overlapped compute
#pragma unroll
        for (int rt = 0; rt < 2; ++rt) { ah[rt] = ah2[rt]; al[rt] = al2[rt]; }
        buf ^= 1;
    }

    // epilogue: wave w holds rows w*32 + rt*16 + quad*4 + reg, cols ct*16+l15.
    // rowmax over ct (regs) then l15 lanes; double-sum this wave's 32 rows.
    double dsum = 0.0;
#pragma unroll
    for (int rt = 0; rt < 2; ++rt) {
        float m[4];
#pragma unroll
        for (int reg = 0; reg < 4; ++reg) {
            float mm = acc[rt][0][reg];
#pragma unroll
            for (int ct = 1; ct < 8; ++ct) mm = fmaxf(mm, acc[rt][ct][reg]);
            m[reg] = mm;
        }
#pragma unroll
        for (int off = 1; off < 16; off <<= 1)
#pragma unroll
            for (int reg = 0; reg < 4; ++reg) m[reg] = fmaxf(m[reg], __shfl_xor(m[reg], off));
#pragma unroll
        for (int reg = 0; reg < 4; ++reg) dsum += (double)m[reg];
    }
    dsum += __shfl_xor(dsum, 16);   // sum over quads (rows quad*4+reg distinct)
    dsum += __shfl_xor(dsum, 32);

    if (lane == 0) sred[w] = dsum;
    __syncthreads();
    if (tid == 0)
        scores[(b * NCHUNK + i) * NCHUNK + j] =
            (float)(sred[0] + sred[1] + sred[2] + sred[3]);
}

// ---------------------------------------------------------------------------
// Stage C: top-7 selection + weights (tiny, serial) — unchanged
// ---------------------------------------------------------------------------
__global__ void topk_kernel(const float* __restrict__ scores,
                            int* __restrict__ ext_idx,
                            float* __restrict__ ext_w) {
    int tid = threadIdx.x;
    if (tid >= NBATCH * NCHUNK) return;
    int b = tid >> 6, i = tid & 63;
    const float* srow = scores + (b * NCHUNK + i) * NCHUNK;

    int nsel = i < KSEL ? i : KSEL;
    float vals[KSEL];
    int   idxs[KSEL];
    unsigned long long used = 0ull;
    for (int s = 0; s < nsel; ++s) {
        float best = -3.0e38f;
        int   bj = 0;
        for (int jj = 0; jj < i; ++jj) {
            if ((used >> jj) & 1ull) continue;
            float v = srow[jj];
            if (v > best) { best = v; bj = jj; }
        }
        used |= 1ull << bj;
        vals[s] = best;
        idxs[s] = bj;
    }
    float vmin = (nsel > 0) ? vals[nsel - 1] : 0.0f;
    float inv  = 1.0f / (vmin + 1e-6f);
    int shift  = KSEL - nsel;
    for (int s = 0; s < KSEL; ++s) {
        int t = s - shift;
        int o = (b * NCHUNK + i) * KSEL + s;
        if (t >= 0) { ext_idx[o] = idxs[t]; ext_w[o] = vals[t] * inv; }
        else        { ext_idx[o] = -1;      ext_w[o] = 0.0f; }
    }
}

// ---------------------------------------------------------------------------
// Stage D v3: out = dp @ ext + chunk, single-pass bf16 MFMA (r7, passed)
// ---------------------------------------------------------------------------
__global__ __launch_bounds__(256) void out_mfma(const float* __restrict__ x,
                                                const short* __restrict__ dph,
                                                const short* __restrict__ xth,
                                                const int* __restrict__ ext_idx,
                                                const float* __restrict__ ext_w,
                                                float* __restrict__ out) {
    __shared__ short As[2][128 * 32];   // [buf][c][k]  8 KB each
    __shared__ short Bs[2][128 * 32];   // [buf][e][k]  8 KB each
    __shared__ int   sjj[8];
    __shared__ float sww[8];
    __shared__ int   slist[8], sslot[8], snum;
    __shared__ float swei[8];

    const int eq = blockIdx.x, n = blockIdx.y, b = blockIdx.z;
    const int e0 = eq * 128;
    const int tid  = threadIdx.x;
    const int w    = tid >> 6, lane = tid & 63;
    const int wr   = w >> 1, wc = w & 1;
    const int quad = lane >> 4, l15 = lane & 15;
    const int rr   = lane >> 2;
    const int c16  = (lane & 3) * 8;

    if (tid < KSEL) {
        sjj[tid] = ext_idx[(b * NCHUNK + n) * KSEL + tid];
        sww[tid] = ext_w [(b * NCHUNK + n) * KSEL + tid];
    }
    if (tid == KSEL) { sjj[KSEL] = n; sww[KSEL] = 1.0f; }
    __syncthreads();
    if (tid == 0) {
        int c = 0;
        for (int s = 0; s < 8; ++s)
            if (sjj[s] >= 0) { slist[c] = sjj[s]; sslot[c] = s; swei[c] = sww[s]; ++c; }
        snum = c;
    }
    __syncthreads();
    const int NS = snum * 4;

    auto stage = [&](int st, int bf) {
        int sv = st >> 2, kk = st & 3;
        if (w < 2) {
            const short* gsrc = dph + (size_t)(sslot[sv] * 128 + kk * 32) + c16;
#pragma unroll
            for (int t = 0; t < 4; ++t)
                gl_lds16(gsrc + (size_t)(w * 64 + t * 16 + rr) * LEXT,
                         &As[bf][(w * 64 + t * 16) * 32]);
        } else {
            const short* gsrc = xth + ((size_t)(b * EDIM + e0)) * TLEN
                                + (size_t)(slist[sv] * CS + kk * 32) + c16;
#pragma unroll
            for (int t = 0; t < 4; ++t)
                gl_lds16(gsrc + (size_t)((w - 2) * 64 + t * 16 + rr) * TLEN,
                         &Bs[bf][((w - 2) * 64 + t * 16) * 32]);
        }
    };

    floatx4 accT[4][4], accP[4][4];
#pragma unroll
    for (int rt = 0; rt < 4; ++rt)
#pragma unroll
        for (int ct = 0; ct < 4; ++ct) accT[rt][ct] = (floatx4){0.f, 0.f, 0.f, 0.f};

    stage(0, 0);
    __syncthreads();

    int buf = 0;
    for (int st = 0; st < NS; ++st) {
        if (st + 1 < NS) stage(st + 1, buf ^ 1);

        if ((st & 3) == 0) {
#pragma unroll
            for (int rt = 0; rt < 4; ++rt)
#pragma unroll
                for (int ct = 0; ct < 4; ++ct) accP[rt][ct] = (floatx4){0.f, 0.f, 0.f, 0.f};
        }

        short8 bh[4];
#pragma unroll
        for (int ct = 0; ct < 4; ++ct) {
            int e = wc * 64 + ct * 16 + l15;
            bh[ct] = *(const short8*)&Bs[buf][e * 32 + quad * 8];
        }
#pragma unroll
        for (int rt = 0; rt < 4; ++rt) {
            int r = wr * 64 + rt * 16 + l15;
            short8 ah = *(const short8*)&As[buf][r * 32 + quad * 8];
#pragma unroll
            for (int ct = 0; ct < 4; ++ct)
                accP[rt][ct] = __builtin_amdgcn_mfma_f32_16x16x32_bf16(ah, bh[ct], accP[rt][ct], 0, 0, 0);
        }

        if ((st & 3) == 3) {
            float wcur = swei[st >> 2];
#pragma unroll
            for (int rt = 0; rt < 4; ++rt)
#pragma unroll
                for (int ct = 0; ct < 4; ++ct)
#pragma unroll
                    for (int reg = 0; reg < 4; ++reg)
                        accT[rt][ct][reg] += wcur * accP[rt][ct][reg];
        }
        __syncthreads();
        buf ^= 1;
    }

#pragma unroll
    for (int rt = 0; rt < 4; ++rt)
#pragma unroll
        for (int ct = 0; ct < 4; ++ct) {
#pragma unroll
            for (int reg = 0; reg < 4; ++reg) {
                int row = wr * 64 + rt * 16 + quad * 4 + reg;
                int col = wc * 64 + ct * 16 + l15;
                size_t o = ((size_t)(b * TLEN + n * CS + row)) * EDIM + e0 + col;
                out[o] = accT[rt][ct][reg] + x[o];
            }
        }
}

// ---------------------------------------------------------------------------
extern "C" void kernel_launch(void* const* d_in, const int* in_sizes, int n_in,
                              void* d_out, int out_size, void* d_ws, size_t ws_size,
                              hipStream_t stream) {
    const float* x  = (const float*)d_in[0];   // [2, 8192, 256] fp32
    const float* dp = (const float*)d_in[1];   // [128, 1024] fp32
    float* out = (float*)d_out;

    char* ws = (char*)d_ws;
    short* cn_hi  = (short*)(ws);                       // 8 MB
    short* cn_lo  = (short*)(ws + (8u << 20));          // 8 MB
    short* xt_hi  = (short*)(ws + (16u << 20));         // 8 MB
    short* dp_hi  = (short*)(ws + (24u << 20));         // 256 KB
    float* scores = (float*)(ws + (25u << 20));         // 32 KB
    int*   ext_idx = (int*)  (ws + (25u << 20) + 32768);
    float* ext_w   = (float*)(ws + (25u << 20) + 32768 + 4096);

    normsplit_kernel<<<dim3(NBATCH * TLEN / 4), 256, 0, stream>>>(x, cn_hi, cn_lo);
    xt_split_kernel <<<dim3(EDIM / 64, TLEN / 64, NBATCH), 256, 0, stream>>>(x, xt_hi);
    dp_split_kernel <<<dim3(CS * LEXT / 1024), 256, 0, stream>>>(dp, dp_hi);
    scores_mfma     <<<dim3(NCHUNK * (NCHUNK - 1) / 2, NBATCH), 256, 0, stream>>>(cn_hi, cn_lo, scores);
    topk_kernel     <<<1, 128, 0, stream>>>(scores, ext_idx, ext_w);
    out_mfma        <<<dim3(2, NCHUNK, NBATCH), 256, 0, stream>>>(x, dp_hi, xt_hi,
                                                                  ext_idx, ext_w, out);
}

// Round 10
// 279.632 us; speedup vs baseline: 1.4263x; 1.4263x over previous
//
#include <hip/hip_runtime.h>
#include <hip/hip_bf16.h>

// Problem constants (fixed by the reference)
#define CS     128
#define EDIM   256
#define NBATCH 2
#define TLEN   8192
#define NCHUNK 64
#define LEXT   1024
#define KSEL   7

typedef __attribute__((ext_vector_type(8))) short   short8;   // 8 bf16 = 4 VGPR (MFMA A/B frag)
typedef __attribute__((ext_vector_type(4))) float   floatx4;  // MFMA C/D frag

__device__ inline short bf16_of(float f) {
    __hip_bfloat16 h = __float2bfloat16(f);
    return *(short*)&h;
}
__device__ inline float f_of_bf16(short s) {
    __hip_bfloat16 h = *(__hip_bfloat16*)&s;
    return __bfloat162float(h);
}

// async global->LDS, 16B per lane; LDS dest = wave-uniform base + lane*16
__device__ inline void gl_lds16(const void* g, void* l) {
    __builtin_amdgcn_global_load_lds(
        (const __attribute__((address_space(1))) unsigned int*)g,
        (__attribute__((address_space(3))) unsigned int*)l, 16, 0, 0);
}

// ---------------------------------------------------------------------------
// Stage A1: normalize rows, split to bf16 hi/lo (for scores). One wave/row.
// ---------------------------------------------------------------------------
__global__ __launch_bounds__(256) void normsplit_kernel(const float* __restrict__ x,
                                                        short* __restrict__ cn_hi,
                                                        short* __restrict__ cn_lo) {
    int row  = blockIdx.x * 4 + (threadIdx.x >> 6);
    int lane = threadIdx.x & 63;
    const float4 v = ((const float4*)(x + (size_t)row * EDIM))[lane];
    float s = v.x * v.x + v.y * v.y + v.z * v.z + v.w * v.w;
#pragma unroll
    for (int off = 1; off < 64; off <<= 1) s += __shfl_xor(s, off);
    float r = 1.0f / (sqrtf(s) + 1e-6f);

    float c[4] = {v.x * r, v.y * r, v.z * r, v.w * r};
    short hs[4], ls[4];
#pragma unroll
    for (int q = 0; q < 4; ++q) {
        hs[q] = bf16_of(c[q]);
        ls[q] = bf16_of(c[q] - f_of_bf16(hs[q]));
    }
    size_t o = (size_t)row * EDIM + lane * 4;
    *(short4*)(cn_hi + o) = make_short4(hs[0], hs[1], hs[2], hs[3]);
    *(short4*)(cn_lo + o) = make_short4(ls[0], ls[1], ls[2], ls[3]);
}

// ---------------------------------------------------------------------------
// Stage A2: down_proj -> bf16 (single-pass: out GEMM needs hi only)
// ---------------------------------------------------------------------------
__global__ __launch_bounds__(256) void dp_split_kernel(const float* __restrict__ dp,
                                                       short* __restrict__ dph) {
    int idx = (blockIdx.x * 256 + threadIdx.x) * 4;
    float4 v = *(const float4*)(dp + idx);
    *(short4*)(dph + idx) = make_short4(bf16_of(v.x), bf16_of(v.y), bf16_of(v.z), bf16_of(v.w));
}

// ---------------------------------------------------------------------------
// Stage A3: transpose x to [b][e][t], bf16 (hi only, for out B-operand)
// ---------------------------------------------------------------------------
__global__ __launch_bounds__(256) void xt_split_kernel(const float* __restrict__ x,
                                                       short* __restrict__ xth) {
    __shared__ float tile[64][68];
    const int e0 = blockIdx.x * 64, t0 = blockIdx.y * 64, b = blockIdx.z;
    const int tid = threadIdx.x;
    const int cr = tid >> 4, cc = (tid & 15) * 4;
#pragma unroll
    for (int p = 0; p < 4; ++p) {
        int r = cr + p * 16;
        float4 v = *(const float4*)(x + ((size_t)(b * TLEN + t0 + r)) * EDIM + e0 + cc);
        *(float4*)&tile[r][cc] = v;
    }
    __syncthreads();
    const int e = tid >> 2, toff = (tid & 3) * 16;
    short hs[16];
#pragma unroll
    for (int q = 0; q < 16; ++q) hs[q] = bf16_of(tile[toff + q][e]);
    size_t o = ((size_t)(b * EDIM + e0 + e)) * TLEN + t0 + toff;
#pragma unroll
    for (int q4 = 0; q4 < 4; ++q4)
        *(short4*)(xth + o + q4 * 4) = make_short4(hs[q4*4], hs[q4*4+1], hs[q4*4+2], hs[q4*4+3]);
}

// ---------------------------------------------------------------------------
// Stage B v6b: pair-per-block (r3 grid: 4032 blocks, 256 thr) with
// restructured K-loop: ONLY B (j-chunk hi+lo) in LDS (double-buffered
// 32 KB), A frags register-direct prefetched one kstep ahead, ONE barrier
// per kstep. v6 (round 9) was correct in structure but spilled: the
// (256,4) launch_bounds min-waves arg capped VGPR at 64 (WRITE_SIZE 442MB
// of scratch). Empirical rule: NO 2nd launch_bounds arg — let the
// allocator pick (~120 VGPR -> 3 blocks/CU, no spill).
// MFMA per-element sequence identical to r3 -> sims bit-identical.
// ---------------------------------------------------------------------------
__global__ __launch_bounds__(256) void scores_mfma(const short* __restrict__ cn_hi,
                                                   const short* __restrict__ cn_lo,
                                                   float* __restrict__ scores) {
    __shared__ short  Bs[2][2][128 * 32];   // [buf][hi/lo][row*32+k] = 32 KB
    __shared__ double sred[4];

    const int p = blockIdx.x, b = blockIdx.y;
    int i = (int)((1.0f + sqrtf(1.0f + 8.0f * (float)p)) * 0.5f);
    while (i * (i - 1) / 2 > p) --i;
    while (i * (i + 1) / 2 <= p) ++i;
    const int j = p - i * (i - 1) / 2;

    const int tid  = threadIdx.x;
    const int w    = tid >> 6, lane = tid & 63;
    const int quad = lane >> 4, l15 = lane & 15;
    const int rr   = lane >> 2, c16 = (lane & 3) * 8;

    // B staging role: waves 0,1 -> hi rows (w&1)*64..+63; waves 2,3 -> lo
    const short* barr  = (w >= 2) ? cn_lo : cn_hi;
    const int    brow0 = (w & 1) * 64;
    const short* bbase = barr + ((size_t)b * TLEN + (size_t)j * CS + brow0) * EDIM + c16;
    const int    bhl   = w >> 1;

    // A compute rows: wave w owns rows w*32 + rt*16 + l15
    const size_t abase = ((size_t)b * TLEN + (size_t)i * CS + w * 32) * EDIM;

    floatx4 acc[2][8];
#pragma unroll
    for (int rt = 0; rt < 2; ++rt)
#pragma unroll
        for (int ct = 0; ct < 8; ++ct) acc[rt][ct] = (floatx4){0.f, 0.f, 0.f, 0.f};

    short8 ah[2], al[2], ah2[2], al2[2];

    // prologue: stage B(0) into buf 0; load A(0)
#pragma unroll
    for (int t = 0; t < 4; ++t)
        gl_lds16(bbase + (size_t)(t * 16 + rr) * EDIM, &Bs[0][bhl][(brow0 + t * 16) * 32]);
#pragma unroll
    for (int rt = 0; rt < 2; ++rt) {
        size_t off = abase + (size_t)(rt * 16 + l15) * EDIM + quad * 8;
        ah[rt] = *(const short8*)(cn_hi + off);
        al[rt] = *(const short8*)(cn_lo + off);
    }
    __syncthreads();

    int buf = 0;
#pragma unroll
    for (int ks = 0; ks < 8; ++ks) {
        if (ks < 7) {
            // stage B(k+1) into other buffer (overlaps compute below)
#pragma unroll
            for (int t = 0; t < 4; ++t)
                gl_lds16(bbase + (size_t)(t * 16 + rr) * EDIM + (ks + 1) * 32,
                         &Bs[buf ^ 1][bhl][(brow0 + t * 16) * 32]);
            // prefetch A(k+1) into registers
#pragma unroll
            for (int rt = 0; rt < 2; ++rt) {
                size_t off = abase + (size_t)(rt * 16 + l15) * EDIM + (ks + 1) * 32 + quad * 8;
                ah2[rt] = *(const short8*)(cn_hi + off);
                al2[rt] = *(const short8*)(cn_lo + off);
            }
        }
        // compute(k) on current buffer
#pragma unroll
        for (int ct = 0; ct < 8; ++ct) {
            const short* pb = &Bs[buf][0][(ct * 16 + l15) * 32 + quad * 8];
            short8 bh = *(const short8*)pb;
            short8 bl = *(const short8*)(pb + 128 * 32);
#pragma unroll
            for (int rt = 0; rt < 2; ++rt) {
                acc[rt][ct] = __builtin_amdgcn_mfma_f32_16x16x32_bf16(ah[rt], bh, acc[rt][ct], 0, 0, 0);
                acc[rt][ct] = __builtin_amdgcn_mfma_f32_16x16x32_bf16(ah[rt], bl, acc[rt][ct], 0, 0, 0);
                acc[rt][ct] = __builtin_amdgcn_mfma_f32_16x16x32_bf16(al[rt], bh, acc[rt][ct], 0, 0, 0);
            }
        }
        __syncthreads();   // B(k+1) staged + buf free; drain overlapped compute
#pragma unroll
        for (int rt = 0; rt < 2; ++rt) { ah[rt] = ah2[rt]; al[rt] = al2[rt]; }
        buf ^= 1;
    }

    // epilogue: wave w holds rows w*32 + rt*16 + quad*4 + reg, cols ct*16+l15.
    // rowmax over ct (regs) then l15 lanes; double-sum this wave's 32 rows.
    double dsum = 0.0;
#pragma unroll
    for (int rt = 0; rt < 2; ++rt) {
        float m[4];
#pragma unroll
        for (int reg = 0; reg < 4; ++reg) {
            float mm = acc[rt][0][reg];
#pragma unroll
            for (int ct = 1; ct < 8; ++ct) mm = fmaxf(mm, acc[rt][ct][reg]);
            m[reg] = mm;
        }
#pragma unroll
        for (int off = 1; off < 16; off <<= 1)
#pragma unroll
            for (int reg = 0; reg < 4; ++reg) m[reg] = fmaxf(m[reg], __shfl_xor(m[reg], off));
#pragma unroll
        for (int reg = 0; reg < 4; ++reg) dsum += (double)m[reg];
    }
    dsum += __shfl_xor(dsum, 16);   // sum over quads (rows quad*4+reg distinct)
    dsum += __shfl_xor(dsum, 32);

    if (lane == 0) sred[w] = dsum;
    __syncthreads();
    if (tid == 0)
        scores[(b * NCHUNK + i) * NCHUNK + j] =
            (float)(sred[0] + sred[1] + sred[2] + sred[3]);
}

// ---------------------------------------------------------------------------
// Stage C: top-7 selection + weights (tiny, serial) — unchanged
// ---------------------------------------------------------------------------
__global__ void topk_kernel(const float* __restrict__ scores,
                            int* __restrict__ ext_idx,
                            float* __restrict__ ext_w) {
    int tid = threadIdx.x;
    if (tid >= NBATCH * NCHUNK) return;
    int b = tid >> 6, i = tid & 63;
    const float* srow = scores + (b * NCHUNK + i) * NCHUNK;

    int nsel = i < KSEL ? i : KSEL;
    float vals[KSEL];
    int   idxs[KSEL];
    unsigned long long used = 0ull;
    for (int s = 0; s < nsel; ++s) {
        float best = -3.0e38f;
        int   bj = 0;
        for (int jj = 0; jj < i; ++jj) {
            if ((used >> jj) & 1ull) continue;
            float v = srow[jj];
            if (v > best) { best = v; bj = jj; }
        }
        used |= 1ull << bj;
        vals[s] = best;
        idxs[s] = bj;
    }
    float vmin = (nsel > 0) ? vals[nsel - 1] : 0.0f;
    float inv  = 1.0f / (vmin + 1e-6f);
    int shift  = KSEL - nsel;
    for (int s = 0; s < KSEL; ++s) {
        int t = s - shift;
        int o = (b * NCHUNK + i) * KSEL + s;
        if (t >= 0) { ext_idx[o] = idxs[t]; ext_w[o] = vals[t] * inv; }
        else        { ext_idx[o] = -1;      ext_w[o] = 0.0f; }
    }
}

// ---------------------------------------------------------------------------
// Stage D v3: out = dp @ ext + chunk, single-pass bf16 MFMA (r7, passed)
// ---------------------------------------------------------------------------
__global__ __launch_bounds__(256) void out_mfma(const float* __restrict__ x,
                                                const short* __restrict__ dph,
                                                const short* __restrict__ xth,
                                                const int* __restrict__ ext_idx,
                                                const float* __restrict__ ext_w,
                                                float* __restrict__ out) {
    __shared__ short As[2][128 * 32];   // [buf][c][k]  8 KB each
    __shared__ short Bs[2][128 * 32];   // [buf][e][k]  8 KB each
    __shared__ int   sjj[8];
    __shared__ float sww[8];
    __shared__ int   slist[8], sslot[8], snum;
    __shared__ float swei[8];

    const int eq = blockIdx.x, n = blockIdx.y, b = blockIdx.z;
    const int e0 = eq * 128;
    const int tid  = threadIdx.x;
    const int w    = tid >> 6, lane = tid & 63;
    const int wr   = w >> 1, wc = w & 1;
    const int quad = lane >> 4, l15 = lane & 15;
    const int rr   = lane >> 2;
    const int c16  = (lane & 3) * 8;

    if (tid < KSEL) {
        sjj[tid] = ext_idx[(b * NCHUNK + n) * KSEL + tid];
        sww[tid] = ext_w [(b * NCHUNK + n) * KSEL + tid];
    }
    if (tid == KSEL) { sjj[KSEL] = n; sww[KSEL] = 1.0f; }
    __syncthreads();
    if (tid == 0) {
        int c = 0;
        for (int s = 0; s < 8; ++s)
            if (sjj[s] >= 0) { slist[c] = sjj[s]; sslot[c] = s; swei[c] = sww[s]; ++c; }
        snum = c;
    }
    __syncthreads();
    const int NS = snum * 4;

    auto stage = [&](int st, int bf) {
        int sv = st >> 2, kk = st & 3;
        if (w < 2) {
            const short* gsrc = dph + (size_t)(sslot[sv] * 128 + kk * 32) + c16;
#pragma unroll
            for (int t = 0; t < 4; ++t)
                gl_lds16(gsrc + (size_t)(w * 64 + t * 16 + rr) * LEXT,
                         &As[bf][(w * 64 + t * 16) * 32]);
        } else {
            const short* gsrc = xth + ((size_t)(b * EDIM + e0)) * TLEN
                                + (size_t)(slist[sv] * CS + kk * 32) + c16;
#pragma unroll
            for (int t = 0; t < 4; ++t)
                gl_lds16(gsrc + (size_t)((w - 2) * 64 + t * 16 + rr) * TLEN,
                         &Bs[bf][((w - 2) * 64 + t * 16) * 32]);
        }
    };

    floatx4 accT[4][4], accP[4][4];
#pragma unroll
    for (int rt = 0; rt < 4; ++rt)
#pragma unroll
        for (int ct = 0; ct < 4; ++ct) accT[rt][ct] = (floatx4){0.f, 0.f, 0.f, 0.f};

    stage(0, 0);
    __syncthreads();

    int buf = 0;
    for (int st = 0; st < NS; ++st) {
        if (st + 1 < NS) stage(st + 1, buf ^ 1);

        if ((st & 3) == 0) {
#pragma unroll
            for (int rt = 0; rt < 4; ++rt)
#pragma unroll
                for (int ct = 0; ct < 4; ++ct) accP[rt][ct] = (floatx4){0.f, 0.f, 0.f, 0.f};
        }

        short8 bh[4];
#pragma unroll
        for (int ct = 0; ct < 4; ++ct) {
            int e = wc * 64 + ct * 16 + l15;
            bh[ct] = *(const short8*)&Bs[buf][e * 32 + quad * 8];
        }
#pragma unroll
        for (int rt = 0; rt < 4; ++rt) {
            int r = wr * 64 + rt * 16 + l15;
            short8 ah = *(const short8*)&As[buf][r * 32 + quad * 8];
#pragma unroll
            for (int ct = 0; ct < 4; ++ct)
                accP[rt][ct] = __builtin_amdgcn_mfma_f32_16x16x32_bf16(ah, bh[ct], accP[rt][ct], 0, 0, 0);
        }

        if ((st & 3) == 3) {
            float wcur = swei[st >> 2];
#pragma unroll
            for (int rt = 0; rt < 4; ++rt)
#pragma unroll
                for (int ct = 0; ct < 4; ++ct)
#pragma unroll
                    for (int reg = 0; reg < 4; ++reg)
                        accT[rt][ct][reg] += wcur * accP[rt][ct][reg];
        }
        __syncthreads();
        buf ^= 1;
    }

#pragma unroll
    for (int rt = 0; rt < 4; ++rt)
#pragma unroll
        for (int ct = 0; ct < 4; ++ct) {
#pragma unroll
            for (int reg = 0; reg < 4; ++reg) {
                int row = wr * 64 + rt * 16 + quad * 4 + reg;
                int col = wc * 64 + ct * 16 + l15;
                size_t o = ((size_t)(b * TLEN + n * CS + row)) * EDIM + e0 + col;
                out[o] = accT[rt][ct][reg] + x[o];
            }
        }
}

// ---------------------------------------------------------------------------
extern "C" void kernel_launch(void* const* d_in, const int* in_sizes, int n_in,
                              void* d_out, int out_size, void* d_ws, size_t ws_size,
                              hipStream_t stream) {
    const float* x  = (const float*)d_in[0];   // [2, 8192, 256] fp32
    const float* dp = (const float*)d_in[1];   // [128, 1024] fp32
    float* out = (float*)d_out;

    char* ws = (char*)d_ws;
    short* cn_hi  = (short*)(ws);                       // 8 MB
    short* cn_lo  = (short*)(ws + (8u << 20));          // 8 MB
    short* xt_hi  = (short*)(ws + (16u << 20));         // 8 MB
    short* dp_hi  = (short*)(ws + (24u << 20));         // 256 KB
    float* scores = (float*)(ws + (25u << 20));         // 32 KB
    int*   ext_idx = (int*)  (ws + (25u << 20) + 32768);
    float* ext_w   = (float*)(ws + (25u << 20) + 32768 + 4096);

    normsplit_kernel<<<dim3(NBATCH * TLEN / 4), 256, 0, stream>>>(x, cn_hi, cn_lo);
    xt_split_kernel <<<dim3(EDIM / 64, TLEN / 64, NBATCH), 256, 0, stream>>>(x, xt_hi);
    dp_split_kernel <<<dim3(CS * LEXT / 1024), 256, 0, stream>>>(dp, dp_hi);
    scores_mfma     <<<dim3(NCHUNK * (NCHUNK - 1) / 2, NBATCH), 256, 0, stream>>>(cn_hi, cn_lo, scores);
    topk_kernel     <<<1, 128, 0, stream>>>(scores, ext_idx, ext_w);
    out_mfma        <<<dim3(2, NCHUNK, NBATCH), 256, 0, stream>>>(x, dp_hi, xt_hi,
                                                                  ext_idx, ext_w, out);
}

// Round 11
// 220.232 us; speedup vs baseline: 1.8109x; 1.2697x over previous
//
#include <hip/hip_runtime.h>
#include <hip/hip_bf16.h>

// Problem constants (fixed by the reference)
#define CS     128
#define EDIM   256
#define NBATCH 2
#define TLEN   8192
#define NCHUNK 64
#define LEXT   1024
#define KSEL   7

typedef __attribute__((ext_vector_type(8))) short   short8;   // 8 bf16 = 4 VGPR (MFMA A/B frag)
typedef __attribute__((ext_vector_type(4))) float   floatx4;  // MFMA C/D frag

__device__ inline short bf16_of(float f) {
    __hip_bfloat16 h = __float2bfloat16(f);
    return *(short*)&h;
}
__device__ inline float f_of_bf16(short s) {
    __hip_bfloat16 h = *(__hip_bfloat16*)&s;
    return __bfloat162float(h);
}

// async global->LDS, 16B per lane; LDS dest = wave-uniform base + lane*16
__device__ inline void gl_lds16(const void* g, void* l) {
    __builtin_amdgcn_global_load_lds(
        (const __attribute__((address_space(1))) unsigned int*)g,
        (__attribute__((address_space(3))) unsigned int*)l, 16, 0, 0);
}

// ---------------------------------------------------------------------------
// Fused prep: one x read -> cn_hi/cn_lo (normalized, split) + xt_hi
// (transposed bf16) ; 8 tail blocks convert dp. Replaces 3 kernels.
// LDS tile pitch 257 floats: transpose column reads are 2-way (free);
// phase-1/3 row accesses 4-way (1.58x, still tiny vs HBM).
// ---------------------------------------------------------------------------
__global__ __launch_bounds__(256) void prep_kernel(const float* __restrict__ x,
                                                   const float* __restrict__ dp,
                                                   short* __restrict__ cn_hi,
                                                   short* __restrict__ cn_lo,
                                                   short* __restrict__ xt_hi,
                                                   short* __restrict__ dp_hi) {
    const int bx = blockIdx.x;
    if (bx >= 256) {            // dp conversion: 8 blocks x 256 thr x 16 float4
        int t = (bx - 256) * 256 + threadIdx.x;
#pragma unroll
        for (int u = 0; u < 16; ++u) {
            int idx = (t * 16 + u) * 4;
            float4 v = *(const float4*)(dp + idx);
            *(short4*)(dp_hi + idx) =
                make_short4(bf16_of(v.x), bf16_of(v.y), bf16_of(v.z), bf16_of(v.w));
        }
        return;
    }

    __shared__ float tile[64 * 257];   // [t-row][e], pitch 257
    const int b = bx >> 7, t0 = (bx & 127) * 64;
    const int tid = threadIdx.x;
    const int r = tid >> 2, q = tid & 3;   // row r (0..63), quarter q (64 elems)

    // phase 1: load row-quarter, sum squares, stash to LDS
    const float* src = x + ((size_t)(b * TLEN + t0 + r)) * EDIM + q * 64;
    float* trow = &tile[r * 257 + q * 64];
    float s = 0.f;
#pragma unroll
    for (int u = 0; u < 16; ++u) {
        float4 v = *(const float4*)(src + u * 4);
        s += v.x * v.x + v.y * v.y + v.z * v.z + v.w * v.w;
        trow[u * 4 + 0] = v.x; trow[u * 4 + 1] = v.y;
        trow[u * 4 + 2] = v.z; trow[u * 4 + 3] = v.w;
    }
    s += __shfl_xor(s, 1);   // lanes r*4+q adjacent: quad reduce = row sum
    s += __shfl_xor(s, 2);
    const float rn = 1.0f / (sqrtf(s) + 1e-6f);

    // phase 2: cn hi/lo for own row-quarter (own LDS data; no barrier needed)
    short* ch = cn_hi + ((size_t)(b * TLEN + t0 + r)) * EDIM + q * 64;
    short* cl = cn_lo + ((size_t)(b * TLEN + t0 + r)) * EDIM + q * 64;
#pragma unroll
    for (int u = 0; u < 16; ++u) {
        short hs[4], ls[4];
#pragma unroll
        for (int k2 = 0; k2 < 4; ++k2) {
            float c = trow[u * 4 + k2] * rn;
            hs[k2] = bf16_of(c);
            ls[k2] = bf16_of(c - f_of_bf16(hs[k2]));
        }
        *(short4*)(ch + u * 4) = make_short4(hs[0], hs[1], hs[2], hs[3]);
        *(short4*)(cl + u * 4) = make_short4(ls[0], ls[1], ls[2], ls[3]);
    }
    __syncthreads();   // full tile resident before transpose reads

    // phase 3: transpose: thread owns e-column, writes xt row segment
    const int e = tid;
    short hs2[64];
#pragma unroll
    for (int t = 0; t < 64; ++t) hs2[t] = bf16_of(tile[t * 257 + e]);
    short* xd = xt_hi + ((size_t)(b * EDIM + e)) * TLEN + t0;
#pragma unroll
    for (int u = 0; u < 16; ++u)
        *(short4*)(xd + u * 4) =
            make_short4(hs2[u * 4], hs2[u * 4 + 1], hs2[u * 4 + 2], hs2[u * 4 + 3]);
}

// ---------------------------------------------------------------------------
// Stage B: split-bf16 MFMA cosine-sim GEMM + rowmax + sum -> scores[b,i,j]
// (exact round-3 kernel — best measured: 128 µs; 5 structural variants all
// landed 128-182 µs -> the ~35% MfmaUtil plateau is structural; keep this.)
// ---------------------------------------------------------------------------
__global__ __launch_bounds__(256) void scores_mfma(const short* __restrict__ cn_hi,
                                                   const short* __restrict__ cn_lo,
                                                   float* __restrict__ scores) {
    __shared__ short  tiles[4][128 * 32];   // 32 KB
    __shared__ float  redbuf[2][128];
    __shared__ double red2[2];

    const int p = blockIdx.x, b = blockIdx.y;
    int i = (int)((1.0f + sqrtf(1.0f + 8.0f * (float)p)) * 0.5f);
    while (i * (i - 1) / 2 > p) --i;
    while (i * (i + 1) / 2 <= p) ++i;
    const int j = p - i * (i - 1) / 2;

    const int tid  = threadIdx.x;
    const int w    = tid >> 6, lane = tid & 63;
    const int wr   = w >> 1, wc = w & 1;
    const int quad = lane >> 4, l15 = lane & 15;

    const short* sarr  = (w & 1) ? cn_lo : cn_hi;
    const size_t sbase = ((size_t)b * TLEN + ((w >> 1) ? j : i) * CS) * EDIM;
    const int rr  = lane >> 2;
    const int c16 = (lane & 3) * 8;

    floatx4 acc[4][4];
#pragma unroll
    for (int rt = 0; rt < 4; ++rt)
#pragma unroll
        for (int ct = 0; ct < 4; ++ct) acc[rt][ct] = (floatx4){0.f, 0.f, 0.f, 0.f};

    for (int ks = 0; ks < 8; ++ks) {
        const short* gsrc = sarr + sbase + ks * 32 + c16;
        short* ldst = &tiles[w][0];
#pragma unroll
        for (int t = 0; t < 8; ++t)
            gl_lds16(gsrc + (size_t)(16 * t + rr) * EDIM, ldst + t * 512);
        __syncthreads();

        short8 bh[4], bl[4];
#pragma unroll
        for (int ct = 0; ct < 4; ++ct) {
            int r = wc * 64 + ct * 16 + l15;
            bh[ct] = *(const short8*)&tiles[2][r * 32 + quad * 8];
            bl[ct] = *(const short8*)&tiles[3][r * 32 + quad * 8];
        }
#pragma unroll
        for (int rt = 0; rt < 4; ++rt) {
            int r = wr * 64 + rt * 16 + l15;
            short8 ah = *(const short8*)&tiles[0][r * 32 + quad * 8];
            short8 al = *(const short8*)&tiles[1][r * 32 + quad * 8];
#pragma unroll
            for (int ct = 0; ct < 4; ++ct) {
                acc[rt][ct] = __builtin_amdgcn_mfma_f32_16x16x32_bf16(ah, bh[ct], acc[rt][ct], 0, 0, 0);
                acc[rt][ct] = __builtin_amdgcn_mfma_f32_16x16x32_bf16(ah, bl[ct], acc[rt][ct], 0, 0, 0);
                acc[rt][ct] = __builtin_amdgcn_mfma_f32_16x16x32_bf16(al, bh[ct], acc[rt][ct], 0, 0, 0);
            }
        }
        __syncthreads();
    }

#pragma unroll
    for (int rt = 0; rt < 4; ++rt) {
        float m[4];
#pragma unroll
        for (int reg = 0; reg < 4; ++reg) {
            float mm = acc[rt][0][reg];
#pragma unroll
            for (int ct = 1; ct < 4; ++ct) mm = fmaxf(mm, acc[rt][ct][reg]);
            m[reg] = mm;
        }
#pragma unroll
        for (int off = 1; off < 16; off <<= 1)
#pragma unroll
            for (int reg = 0; reg < 4; ++reg) m[reg] = fmaxf(m[reg], __shfl_xor(m[reg], off));
        if (l15 == 0) {
#pragma unroll
            for (int reg = 0; reg < 4; ++reg)
                redbuf[wc][wr * 64 + rt * 16 + quad * 4 + reg] = m[reg];
        }
    }
    __syncthreads();

    double part = 0.0;
    if (tid < 128) part = (double)fmaxf(redbuf[0][tid], redbuf[1][tid]);
#pragma unroll
    for (int off = 1; off < 64; off <<= 1) part += __shfl_xor(part, off);
    if (lane == 0 && w < 2) red2[w] = part;
    __syncthreads();
    if (tid == 0) scores[(b * NCHUNK + i) * NCHUNK + j] = (float)(red2[0] + red2[1]);
}

// ---------------------------------------------------------------------------
// Stage D v4: out = dp @ ext + chunk, single-pass bf16 MFMA, with the
// top-k selection INLINED (wave-parallel arg-max, tie -> lowest index ==
// serial strict-> scan; weights/shift identical to the old topk_kernel).
// Kills one kernel launch; selection recomputed per block (cheap, ~1 µs).
// ---------------------------------------------------------------------------
__global__ __launch_bounds__(256) void out_mfma(const float* __restrict__ x,
                                                const short* __restrict__ dph,
                                                const short* __restrict__ xth,
                                                const float* __restrict__ scores,
                                                float* __restrict__ out) {
    __shared__ short As[2][128 * 32];   // [buf][c][k]  8 KB each
    __shared__ short Bs[2][128 * 32];   // [buf][e][k]  8 KB each
    __shared__ int   slist[8], sslot[8], snum;
    __shared__ float swei[8];

    const int eq = blockIdx.x, n = blockIdx.y, b = blockIdx.z;
    const int e0 = eq * 128;
    const int tid  = threadIdx.x;
    const int w    = tid >> 6, lane = tid & 63;
    const int wr   = w >> 1, wc = w & 1;
    const int quad = lane >> 4, l15 = lane & 15;
    const int rr   = lane >> 2;
    const int c16  = (lane & 3) * 8;

    // ---- inlined top-7 (wave 0): candidates j in [0, n) ----
    if (w == 0) {
        const float* srow = scores + (b * NCHUNK + n) * NCHUNK;
        const int nsel = n < KSEL ? n : KSEL;
        float v = (lane < n) ? srow[lane] : -3.0e38f;
        float vals[KSEL];
        int   idxs[KSEL];
        for (int s2 = 0; s2 < nsel; ++s2) {
            float bv = v; int bi = lane;
#pragma unroll
            for (int off = 1; off < 64; off <<= 1) {
                float ov = __shfl_xor(bv, off);
                int   oi = __shfl_xor(bi, off);
                if (ov > bv || (ov == bv && oi < bi)) { bv = ov; bi = oi; }
            }
            vals[s2] = bv; idxs[s2] = bi;
            if (lane == bi) v = -3.0e38f;
        }
        if (lane == 0) {
            float vmin = (nsel > 0) ? vals[nsel - 1] : 0.0f;
            float inv  = 1.0f / (vmin + 1e-6f);
            int shift  = KSEL - nsel;
            int c = 0;
            for (int s2 = 0; s2 < 8; ++s2) {
                int jj; float ww;
                if (s2 < KSEL) {
                    int tt = s2 - shift;
                    if (tt >= 0) { jj = idxs[tt]; ww = vals[tt] * inv; }
                    else         { jj = -1;       ww = 0.0f; }
                } else { jj = n; ww = 1.0f; }
                if (jj >= 0) { slist[c] = jj; sslot[c] = s2; swei[c] = ww; ++c; }
            }
            snum = c;
        }
    }
    __syncthreads();
    const int NS = snum * 4;   // flattened steps (kk=0..3 per valid slot)

    auto stage = [&](int st, int bf) {
        int sv = st >> 2, kk = st & 3;
        if (w < 2) {
            const short* gsrc = dph + (size_t)(sslot[sv] * 128 + kk * 32) + c16;
#pragma unroll
            for (int t = 0; t < 4; ++t)
                gl_lds16(gsrc + (size_t)(w * 64 + t * 16 + rr) * LEXT,
                         &As[bf][(w * 64 + t * 16) * 32]);
        } else {
            const short* gsrc = xth + ((size_t)(b * EDIM + e0)) * TLEN
                                + (size_t)(slist[sv] * CS + kk * 32) + c16;
#pragma unroll
            for (int t = 0; t < 4; ++t)
                gl_lds16(gsrc + (size_t)((w - 2) * 64 + t * 16 + rr) * TLEN,
                         &Bs[bf][((w - 2) * 64 + t * 16) * 32]);
        }
    };

    floatx4 accT[4][4], accP[4][4];
#pragma unroll
    for (int rt = 0; rt < 4; ++rt)
#pragma unroll
        for (int ct = 0; ct < 4; ++ct) accT[rt][ct] = (floatx4){0.f, 0.f, 0.f, 0.f};

    stage(0, 0);
    __syncthreads();

    int buf = 0;
    for (int st = 0; st < NS; ++st) {
        if (st + 1 < NS) stage(st + 1, buf ^ 1);

        if ((st & 3) == 0) {
#pragma unroll
            for (int rt = 0; rt < 4; ++rt)
#pragma unroll
                for (int ct = 0; ct < 4; ++ct) accP[rt][ct] = (floatx4){0.f, 0.f, 0.f, 0.f};
        }

        short8 bh[4];
#pragma unroll
        for (int ct = 0; ct < 4; ++ct) {
            int e = wc * 64 + ct * 16 + l15;
            bh[ct] = *(const short8*)&Bs[buf][e * 32 + quad * 8];
        }
#pragma unroll
        for (int rt = 0; rt < 4; ++rt) {
            int r = wr * 64 + rt * 16 + l15;
            short8 ah = *(const short8*)&As[buf][r * 32 + quad * 8];
#pragma unroll
            for (int ct = 0; ct < 4; ++ct)
                accP[rt][ct] = __builtin_amdgcn_mfma_f32_16x16x32_bf16(ah, bh[ct], accP[rt][ct], 0, 0, 0);
        }

        if ((st & 3) == 3) {
            float wcur = swei[st >> 2];
#pragma unroll
            for (int rt = 0; rt < 4; ++rt)
#pragma unroll
                for (int ct = 0; ct < 4; ++ct)
#pragma unroll
                    for (int reg = 0; reg < 4; ++reg)
                        accT[rt][ct][reg] += wcur * accP[rt][ct][reg];
        }
        __syncthreads();
        buf ^= 1;
    }

#pragma unroll
    for (int rt = 0; rt < 4; ++rt)
#pragma unroll
        for (int ct = 0; ct < 4; ++ct) {
#pragma unroll
            for (int reg = 0; reg < 4; ++reg) {
                int row = wr * 64 + rt * 16 + quad * 4 + reg;
                int col = wc * 64 + ct * 16 + l15;
                size_t o = ((size_t)(b * TLEN + n * CS + row)) * EDIM + e0 + col;
                out[o] = accT[rt][ct][reg] + x[o];
            }
        }
}

// ---------------------------------------------------------------------------
extern "C" void kernel_launch(void* const* d_in, const int* in_sizes, int n_in,
                              void* d_out, int out_size, void* d_ws, size_t ws_size,
                              hipStream_t stream) {
    const float* x  = (const float*)d_in[0];   // [2, 8192, 256] fp32
    const float* dp = (const float*)d_in[1];   // [128, 1024] fp32
    float* out = (float*)d_out;

    char* ws = (char*)d_ws;
    short* cn_hi  = (short*)(ws);                       // 8 MB
    short* cn_lo  = (short*)(ws + (8u << 20));          // 8 MB
    short* xt_hi  = (short*)(ws + (16u << 20));         // 8 MB
    short* dp_hi  = (short*)(ws + (24u << 20));         // 256 KB
    float* scores = (float*)(ws + (25u << 20));         // 32 KB

    prep_kernel <<<dim3(264), 256, 0, stream>>>(x, dp, cn_hi, cn_lo, xt_hi, dp_hi);
    scores_mfma <<<dim3(NCHUNK * (NCHUNK - 1) / 2, NBATCH), 256, 0, stream>>>(cn_hi, cn_lo, scores);
    out_mfma    <<<dim3(2, NCHUNK, NBATCH), 256, 0, stream>>>(x, dp_hi, xt_hi, scores, out);
}

// Round 12
// 217.344 us; speedup vs baseline: 1.8350x; 1.0133x over previous
//
#include <hip/hip_runtime.h>
#include <hip/hip_bf16.h>

// Problem constants (fixed by the reference)
#define CS     128
#define EDIM   256
#define NBATCH 2
#define TLEN   8192
#define NCHUNK 64
#define LEXT   1024
#define KSEL   7

typedef __attribute__((ext_vector_type(8))) short   short8;   // 8 bf16 = 4 VGPR (MFMA A/B frag)
typedef __attribute__((ext_vector_type(4))) float   floatx4;  // MFMA C/D frag

__device__ inline short bf16_of(float f) {
    __hip_bfloat16 h = __float2bfloat16(f);
    return *(short*)&h;
}
__device__ inline float f_of_bf16(short s) {
    __hip_bfloat16 h = *(__hip_bfloat16*)&s;
    return __bfloat162float(h);
}

// async global->LDS, 16B per lane; LDS dest = wave-uniform base + lane*16
__device__ inline void gl_lds16(const void* g, void* l) {
    __builtin_amdgcn_global_load_lds(
        (const __attribute__((address_space(1))) unsigned int*)g,
        (__attribute__((address_space(3))) unsigned int*)l, 16, 0, 0);
}

// ---------------------------------------------------------------------------
// Fused prep: one x read -> cn_hi/cn_lo + xt_hi ; 8 tail blocks convert dp.
// Phase-3 transpose writes remapped for coalescing: wave = 4 x 128B
// contiguous segments (was 64 x 8B scatter). Values identical to r11.
// ---------------------------------------------------------------------------
__global__ __launch_bounds__(256) void prep_kernel(const float* __restrict__ x,
                                                   const float* __restrict__ dp,
                                                   short* __restrict__ cn_hi,
                                                   short* __restrict__ cn_lo,
                                                   short* __restrict__ xt_hi,
                                                   short* __restrict__ dp_hi) {
    const int bx = blockIdx.x;
    if (bx >= 256) {            // dp conversion: 8 blocks x 256 thr x 16 float4
        int t = (bx - 256) * 256 + threadIdx.x;
#pragma unroll
        for (int u = 0; u < 16; ++u) {
            int idx = (t * 16 + u) * 4;
            float4 v = *(const float4*)(dp + idx);
            *(short4*)(dp_hi + idx) =
                make_short4(bf16_of(v.x), bf16_of(v.y), bf16_of(v.z), bf16_of(v.w));
        }
        return;
    }

    __shared__ float tile[64 * 257];   // [t-row][e], pitch 257
    const int b = bx >> 7, t0 = (bx & 127) * 64;
    const int tid = threadIdx.x;
    const int r = tid >> 2, q = tid & 3;   // row r (0..63), quarter q (64 elems)

    // phase 1: load row-quarter, sum squares, stash to LDS
    const float* src = x + ((size_t)(b * TLEN + t0 + r)) * EDIM + q * 64;
    float* trow = &tile[r * 257 + q * 64];
    float s = 0.f;
#pragma unroll
    for (int u = 0; u < 16; ++u) {
        float4 v = *(const float4*)(src + u * 4);
        s += v.x * v.x + v.y * v.y + v.z * v.z + v.w * v.w;
        trow[u * 4 + 0] = v.x; trow[u * 4 + 1] = v.y;
        trow[u * 4 + 2] = v.z; trow[u * 4 + 3] = v.w;
    }
    s += __shfl_xor(s, 1);   // lanes r*4+q adjacent: quad reduce = row sum
    s += __shfl_xor(s, 2);
    const float rn = 1.0f / (sqrtf(s) + 1e-6f);

    // phase 2: cn hi/lo for own row-quarter (own LDS data; no barrier needed)
    short* ch = cn_hi + ((size_t)(b * TLEN + t0 + r)) * EDIM + q * 64;
    short* cl = cn_lo + ((size_t)(b * TLEN + t0 + r)) * EDIM + q * 64;
#pragma unroll
    for (int u = 0; u < 16; ++u) {
        short hs[4], ls[4];
#pragma unroll
        for (int k2 = 0; k2 < 4; ++k2) {
            float c = trow[u * 4 + k2] * rn;
            hs[k2] = bf16_of(c);
            ls[k2] = bf16_of(c - f_of_bf16(hs[k2]));
        }
        *(short4*)(ch + u * 4) = make_short4(hs[0], hs[1], hs[2], hs[3]);
        *(short4*)(cl + u * 4) = make_short4(ls[0], ls[1], ls[2], ls[3]);
    }
    __syncthreads();   // full tile resident before transpose reads

    // phase 3: coalesced transpose: lane group (g16 = e mod 16, tq) writes
    // short4 at xt[e][t0 + tq*4]; wave = 4 contiguous 128B segments.
    const int g16 = tid >> 4, tq = tid & 15;
#pragma unroll
    for (int it = 0; it < 16; ++it) {
        int e = g16 + it * 16;
        short hs2[4];
#pragma unroll
        for (int g = 0; g < 4; ++g)
            hs2[g] = bf16_of(tile[(tq * 4 + g) * 257 + e]);
        *(short4*)(xt_hi + ((size_t)(b * EDIM + e)) * TLEN + t0 + tq * 4)
            = make_short4(hs2[0], hs2[1], hs2[2], hs2[3]);
    }
}

// ---------------------------------------------------------------------------
// Stage B: split-bf16 MFMA cosine scores (r3 structure, best measured).
// NEW: reduction buffers aliased into the (dead-after-loop) tiles array ->
// LDS exactly 32768 B -> 5 blocks/CU (was 4 at 34304). Barrier-drain-bound
// kernel: +25% co-resident blocks = more drain overlap.
// ---------------------------------------------------------------------------
__global__ __launch_bounds__(256) void scores_mfma(const short* __restrict__ cn_hi,
                                                   const short* __restrict__ cn_lo,
                                                   float* __restrict__ scores) {
    __shared__ short tiles[4][4096];            // 32 KB exactly; no other LDS
    double* red2  = (double*)&tiles[0][0];      // alias (epilogue only)
    float*  redbuf = (float*)&tiles[0][8];      // alias, bytes [16, 1040)

    const int p = blockIdx.x, b = blockIdx.y;
    int i = (int)((1.0f + sqrtf(1.0f + 8.0f * (float)p)) * 0.5f);
    while (i * (i - 1) / 2 > p) --i;
    while (i * (i + 1) / 2 <= p) ++i;
    const int j = p - i * (i - 1) / 2;

    const int tid  = threadIdx.x;
    const int w    = tid >> 6, lane = tid & 63;
    const int wr   = w >> 1, wc = w & 1;
    const int quad = lane >> 4, l15 = lane & 15;

    const short* sarr  = (w & 1) ? cn_lo : cn_hi;
    const size_t sbase = ((size_t)b * TLEN + ((w >> 1) ? j : i) * CS) * EDIM;
    const int rr  = lane >> 2;
    const int c16 = (lane & 3) * 8;

    floatx4 acc[4][4];
#pragma unroll
    for (int rt = 0; rt < 4; ++rt)
#pragma unroll
        for (int ct = 0; ct < 4; ++ct) acc[rt][ct] = (floatx4){0.f, 0.f, 0.f, 0.f};

    for (int ks = 0; ks < 8; ++ks) {
        const short* gsrc = sarr + sbase + ks * 32 + c16;
        short* ldst = &tiles[w][0];
#pragma unroll
        for (int t = 0; t < 8; ++t)
            gl_lds16(gsrc + (size_t)(16 * t + rr) * EDIM, ldst + t * 512);
        __syncthreads();

        short8 bh[4], bl[4];
#pragma unroll
        for (int ct = 0; ct < 4; ++ct) {
            int r = wc * 64 + ct * 16 + l15;
            bh[ct] = *(const short8*)&tiles[2][r * 32 + quad * 8];
            bl[ct] = *(const short8*)&tiles[3][r * 32 + quad * 8];
        }
#pragma unroll
        for (int rt = 0; rt < 4; ++rt) {
            int r = wr * 64 + rt * 16 + l15;
            short8 ah = *(const short8*)&tiles[0][r * 32 + quad * 8];
            short8 al = *(const short8*)&tiles[1][r * 32 + quad * 8];
#pragma unroll
            for (int ct = 0; ct < 4; ++ct) {
                acc[rt][ct] = __builtin_amdgcn_mfma_f32_16x16x32_bf16(ah, bh[ct], acc[rt][ct], 0, 0, 0);
                acc[rt][ct] = __builtin_amdgcn_mfma_f32_16x16x32_bf16(ah, bl[ct], acc[rt][ct], 0, 0, 0);
                acc[rt][ct] = __builtin_amdgcn_mfma_f32_16x16x32_bf16(al, bh[ct], acc[rt][ct], 0, 0, 0);
            }
        }
        __syncthreads();   // also protects tiles before the aliased epilogue writes
    }

#pragma unroll
    for (int rt = 0; rt < 4; ++rt) {
        float m[4];
#pragma unroll
        for (int reg = 0; reg < 4; ++reg) {
            float mm = acc[rt][0][reg];
#pragma unroll
            for (int ct = 1; ct < 4; ++ct) mm = fmaxf(mm, acc[rt][ct][reg]);
            m[reg] = mm;
        }
#pragma unroll
        for (int off = 1; off < 16; off <<= 1)
#pragma unroll
            for (int reg = 0; reg < 4; ++reg) m[reg] = fmaxf(m[reg], __shfl_xor(m[reg], off));
        if (l15 == 0) {
#pragma unroll
            for (int reg = 0; reg < 4; ++reg)
                redbuf[wc * 128 + wr * 64 + rt * 16 + quad * 4 + reg] = m[reg];
        }
    }
    __syncthreads();

    double part = 0.0;
    if (tid < 128) part = (double)fmaxf(redbuf[tid], redbuf[128 + tid]);
#pragma unroll
    for (int off = 1; off < 64; off <<= 1) part += __shfl_xor(part, off);
    if (lane == 0 && w < 2) red2[w] = part;
    __syncthreads();
    if (tid == 0) scores[(b * NCHUNK + i) * NCHUNK + j] = (float)(red2[0] + red2[1]);
}

// ---------------------------------------------------------------------------
// Stage D v5: out = dp @ ext + chunk, single-pass bf16 MFMA, inlined top-k.
// e-tile 64 -> grid (4,64,2) = 512 blocks = 2 blocks/CU (was 1/CU): the
// per-step barrier drain now overlaps the co-resident block. Per-slot
// K-sequence unchanged -> out bit-identical to r11.
// ---------------------------------------------------------------------------
__global__ __launch_bounds__(256) void out_mfma(const float* __restrict__ x,
                                                const short* __restrict__ dph,
                                                const short* __restrict__ xth,
                                                const float* __restrict__ scores,
                                                float* __restrict__ out) {
    __shared__ short As[2][128 * 32];   // [buf][c][k]  8 KB each
    __shared__ short Bs[2][64 * 32];    // [buf][e][k]  4 KB each
    __shared__ int   slist[8], sslot[8], snum;
    __shared__ float swei[8];

    const int eq = blockIdx.x, n = blockIdx.y, b = blockIdx.z;
    const int e0 = eq * 64;
    const int tid  = threadIdx.x;
    const int w    = tid >> 6, lane = tid & 63;
    const int wr   = w >> 1, wc = w & 1;
    const int quad = lane >> 4, l15 = lane & 15;
    const int rr   = lane >> 2;
    const int c16  = (lane & 3) * 8;

    // ---- inlined top-7 (wave 0): candidates j in [0, n) ----
    if (w == 0) {
        const float* srow = scores + (b * NCHUNK + n) * NCHUNK;
        const int nsel = n < KSEL ? n : KSEL;
        float v = (lane < n) ? srow[lane] : -3.0e38f;
        float vals[KSEL];
        int   idxs[KSEL];
        for (int s2 = 0; s2 < nsel; ++s2) {
            float bv = v; int bi = lane;
#pragma unroll
            for (int off = 1; off < 64; off <<= 1) {
                float ov = __shfl_xor(bv, off);
                int   oi = __shfl_xor(bi, off);
                if (ov > bv || (ov == bv && oi < bi)) { bv = ov; bi = oi; }
            }
            vals[s2] = bv; idxs[s2] = bi;
            if (lane == bi) v = -3.0e38f;
        }
        if (lane == 0) {
            float vmin = (nsel > 0) ? vals[nsel - 1] : 0.0f;
            float inv  = 1.0f / (vmin + 1e-6f);
            int shift  = KSEL - nsel;
            int c = 0;
            for (int s2 = 0; s2 < 8; ++s2) {
                int jj; float ww;
                if (s2 < KSEL) {
                    int tt = s2 - shift;
                    if (tt >= 0) { jj = idxs[tt]; ww = vals[tt] * inv; }
                    else         { jj = -1;       ww = 0.0f; }
                } else { jj = n; ww = 1.0f; }
                if (jj >= 0) { slist[c] = jj; sslot[c] = s2; swei[c] = ww; ++c; }
            }
            snum = c;
        }
    }
    __syncthreads();
    const int NS = snum * 4;   // flattened steps (kk=0..3 per valid slot)

    // staging: waves 0,1 -> A rows w*64..+63 (dp, 4 gl_lds each);
    //          waves 2,3 -> B rows (w-2)*32..+31 (xT, 2 gl_lds each)
    auto stage = [&](int st, int bf) {
        int sv = st >> 2, kk = st & 3;
        if (w < 2) {
            const short* gsrc = dph + (size_t)(sslot[sv] * 128 + kk * 32) + c16;
#pragma unroll
            for (int t = 0; t < 4; ++t)
                gl_lds16(gsrc + (size_t)(w * 64 + t * 16 + rr) * LEXT,
                         &As[bf][(w * 64 + t * 16) * 32]);
        } else {
            const short* gsrc = xth + ((size_t)(b * EDIM + e0)) * TLEN
                                + (size_t)(slist[sv] * CS + kk * 32) + c16;
#pragma unroll
            for (int t = 0; t < 2; ++t)
                gl_lds16(gsrc + (size_t)((w - 2) * 32 + t * 16 + rr) * TLEN,
                         &Bs[bf][((w - 2) * 32 + t * 16) * 32]);
        }
    };

    floatx4 accT[4][2], accP[4][2];
#pragma unroll
    for (int rt = 0; rt < 4; ++rt)
#pragma unroll
        for (int ct = 0; ct < 2; ++ct) accT[rt][ct] = (floatx4){0.f, 0.f, 0.f, 0.f};

    stage(0, 0);
    __syncthreads();

    int buf = 0;
    for (int st = 0; st < NS; ++st) {
        if (st + 1 < NS) stage(st + 1, buf ^ 1);

        if ((st & 3) == 0) {
#pragma unroll
            for (int rt = 0; rt < 4; ++rt)
#pragma unroll
                for (int ct = 0; ct < 2; ++ct) accP[rt][ct] = (floatx4){0.f, 0.f, 0.f, 0.f};
        }

        short8 bh[2];
#pragma unroll
        for (int ct = 0; ct < 2; ++ct) {
            int e = wc * 32 + ct * 16 + l15;
            bh[ct] = *(const short8*)&Bs[buf][e * 32 + quad * 8];
        }
#pragma unroll
        for (int rt = 0; rt < 4; ++rt) {
            int r = wr * 64 + rt * 16 + l15;
            short8 ah = *(const short8*)&As[buf][r * 32 + quad * 8];
#pragma unroll
            for (int ct = 0; ct < 2; ++ct)
                accP[rt][ct] = __builtin_amdgcn_mfma_f32_16x16x32_bf16(ah, bh[ct], accP[rt][ct], 0, 0, 0);
        }

        if ((st & 3) == 3) {
            float wcur = swei[st >> 2];
#pragma unroll
            for (int rt = 0; rt < 4; ++rt)
#pragma unroll
                for (int ct = 0; ct < 2; ++ct)
#pragma unroll
                    for (int reg = 0; reg < 4; ++reg)
                        accT[rt][ct][reg] += wcur * accP[rt][ct][reg];
        }
        __syncthreads();
        buf ^= 1;
    }

    // epilogue: D[row = wr*64+rt*16+quad*4+reg][col = wc*32+ct*16+l15] + chunk
#pragma unroll
    for (int rt = 0; rt < 4; ++rt)
#pragma unroll
        for (int ct = 0; ct < 2; ++ct) {
#pragma unroll
            for (int reg = 0; reg < 4; ++reg) {
                int row = wr * 64 + rt * 16 + quad * 4 + reg;
                int col = wc * 32 + ct * 16 + l15;
                size_t o = ((size_t)(b * TLEN + n * CS + row)) * EDIM + e0 + col;
                out[o] = accT[rt][ct][reg] + x[o];
            }
        }
}

// ---------------------------------------------------------------------------
extern "C" void kernel_launch(void* const* d_in, const int* in_sizes, int n_in,
                              void* d_out, int out_size, void* d_ws, size_t ws_size,
                              hipStream_t stream) {
    const float* x  = (const float*)d_in[0];   // [2, 8192, 256] fp32
    const float* dp = (const float*)d_in[1];   // [128, 1024] fp32
    float* out = (float*)d_out;

    char* ws = (char*)d_ws;
    short* cn_hi  = (short*)(ws);                       // 8 MB
    short* cn_lo  = (short*)(ws + (8u << 20));          // 8 MB
    short* xt_hi  = (short*)(ws + (16u << 20));         // 8 MB
    short* dp_hi  = (short*)(ws + (24u << 20));         // 256 KB
    float* scores = (float*)(ws + (25u << 20));         // 32 KB

    prep_kernel <<<dim3(264), 256, 0, stream>>>(x, dp, cn_hi, cn_lo, xt_hi, dp_hi);
    scores_mfma <<<dim3(NCHUNK * (NCHUNK - 1) / 2, NBATCH), 256, 0, stream>>>(cn_hi, cn_lo, scores);
    out_mfma    <<<dim3(4, NCHUNK, NBATCH), 256, 0, stream>>>(x, dp_hi, xt_hi, scores, out);
}

// Round 13
// 213.398 us; speedup vs baseline: 1.8689x; 1.0185x over previous
//
#include <hip/hip_runtime.h>
#include <hip/hip_bf16.h>

// Problem constants (fixed by the reference)
#define CS     128
#define EDIM   256
#define NBATCH 2
#define TLEN   8192
#define NCHUNK 64
#define LEXT   1024
#define KSEL   7

typedef __attribute__((ext_vector_type(8))) short   short8;   // 8 bf16 = 4 VGPR (MFMA A/B frag)
typedef __attribute__((ext_vector_type(4))) float   floatx4;  // MFMA C/D frag

__device__ inline short bf16_of(float f) {
    __hip_bfloat16 h = __float2bfloat16(f);
    return *(short*)&h;
}
__device__ inline float f_of_bf16(short s) {
    __hip_bfloat16 h = *(__hip_bfloat16*)&s;
    return __bfloat162float(h);
}

// async global->LDS, 16B per lane; LDS dest = wave-uniform base + lane*16
__device__ inline void gl_lds16(const void* g, void* l) {
    __builtin_amdgcn_global_load_lds(
        (const __attribute__((address_space(1))) unsigned int*)g,
        (__attribute__((address_space(3))) unsigned int*)l, 16, 0, 0);
}

// ---------------------------------------------------------------------------
// Fused prep: one x read -> cn_hi/cn_lo + xt_hi ; 8 tail blocks convert dp.
// (r12 version, passed)
// ---------------------------------------------------------------------------
__global__ __launch_bounds__(256) void prep_kernel(const float* __restrict__ x,
                                                   const float* __restrict__ dp,
                                                   short* __restrict__ cn_hi,
                                                   short* __restrict__ cn_lo,
                                                   short* __restrict__ xt_hi,
                                                   short* __restrict__ dp_hi) {
    const int bx = blockIdx.x;
    if (bx >= 256) {            // dp conversion: 8 blocks x 256 thr x 16 float4
        int t = (bx - 256) * 256 + threadIdx.x;
#pragma unroll
        for (int u = 0; u < 16; ++u) {
            int idx = (t * 16 + u) * 4;
            float4 v = *(const float4*)(dp + idx);
            *(short4*)(dp_hi + idx) =
                make_short4(bf16_of(v.x), bf16_of(v.y), bf16_of(v.z), bf16_of(v.w));
        }
        return;
    }

    __shared__ float tile[64 * 257];   // [t-row][e], pitch 257
    const int b = bx >> 7, t0 = (bx & 127) * 64;
    const int tid = threadIdx.x;
    const int r = tid >> 2, q = tid & 3;   // row r (0..63), quarter q (64 elems)

    const float* src = x + ((size_t)(b * TLEN + t0 + r)) * EDIM + q * 64;
    float* trow = &tile[r * 257 + q * 64];
    float s = 0.f;
#pragma unroll
    for (int u = 0; u < 16; ++u) {
        float4 v = *(const float4*)(src + u * 4);
        s += v.x * v.x + v.y * v.y + v.z * v.z + v.w * v.w;
        trow[u * 4 + 0] = v.x; trow[u * 4 + 1] = v.y;
        trow[u * 4 + 2] = v.z; trow[u * 4 + 3] = v.w;
    }
    s += __shfl_xor(s, 1);
    s += __shfl_xor(s, 2);
    const float rn = 1.0f / (sqrtf(s) + 1e-6f);

    short* ch = cn_hi + ((size_t)(b * TLEN + t0 + r)) * EDIM + q * 64;
    short* cl = cn_lo + ((size_t)(b * TLEN + t0 + r)) * EDIM + q * 64;
#pragma unroll
    for (int u = 0; u < 16; ++u) {
        short hs[4], ls[4];
#pragma unroll
        for (int k2 = 0; k2 < 4; ++k2) {
            float c = trow[u * 4 + k2] * rn;
            hs[k2] = bf16_of(c);
            ls[k2] = bf16_of(c - f_of_bf16(hs[k2]));
        }
        *(short4*)(ch + u * 4) = make_short4(hs[0], hs[1], hs[2], hs[3]);
        *(short4*)(cl + u * 4) = make_short4(ls[0], ls[1], ls[2], ls[3]);
    }
    __syncthreads();

    const int g16 = tid >> 4, tq = tid & 15;
#pragma unroll
    for (int it = 0; it < 16; ++it) {
        int e = g16 + it * 16;
        short hs2[4];
#pragma unroll
        for (int g = 0; g < 4; ++g)
            hs2[g] = bf16_of(tile[(tq * 4 + g) * 257 + e]);
        *(short4*)(xt_hi + ((size_t)(b * EDIM + e)) * TLEN + t0 + tq * 4)
            = make_short4(hs2[0], hs2[1], hs2[2], hs2[3]);
    }
}

// ---------------------------------------------------------------------------
// Stage B: split-bf16 MFMA cosine scores (r3 structure) + XOR bank swizzle:
// LDS[r][c] = G[r][c ^ 8*((r>>1)&3)]. Staging loads from swizzled global
// column (gl_lds dest untouched); frag reads use col8 = quad ^ ((l15>>1)&3)
// -> 16 l15-lanes spread 2-per-4-bank-group = 2-way = free (was 8 lanes per
// group = 4 extra cyc per b128; measured 2048 conflict cyc/block).
// Register values bit-identical -> scores bit-identical.
// ---------------------------------------------------------------------------
__global__ __launch_bounds__(256) void scores_mfma(const short* __restrict__ cn_hi,
                                                   const short* __restrict__ cn_lo,
                                                   float* __restrict__ scores) {
    __shared__ short tiles[4][4096];            // 32 KB exactly; no other LDS
    double* red2  = (double*)&tiles[0][0];      // alias (epilogue only)
    float*  redbuf = (float*)&tiles[0][8];      // alias, bytes [16, 1040)

    const int p = blockIdx.x, b = blockIdx.y;
    int i = (int)((1.0f + sqrtf(1.0f + 8.0f * (float)p)) * 0.5f);
    while (i * (i - 1) / 2 > p) --i;
    while (i * (i + 1) / 2 <= p) ++i;
    const int j = p - i * (i - 1) / 2;

    const int tid  = threadIdx.x;
    const int w    = tid >> 6, lane = tid & 63;
    const int wr   = w >> 1, wc = w & 1;
    const int quad = lane >> 4, l15 = lane & 15;

    const short* sarr  = (w & 1) ? cn_lo : cn_hi;
    const size_t sbase = ((size_t)b * TLEN + ((w >> 1) ? j : i) * CS) * EDIM;
    const int rr  = lane >> 2;
    const int c16 = (lane & 3) * 8;
    const int csw = c16 ^ (((rr >> 1) & 3) * 8);       // staging swizzle
    const int q8  = (quad ^ ((l15 >> 1) & 3)) * 8;     // frag-read swizzle

    floatx4 acc[4][4];
#pragma unroll
    for (int rt = 0; rt < 4; ++rt)
#pragma unroll
        for (int ct = 0; ct < 4; ++ct) acc[rt][ct] = (floatx4){0.f, 0.f, 0.f, 0.f};

    for (int ks = 0; ks < 8; ++ks) {
        const short* gsrc = sarr + sbase + ks * 32 + csw;
        short* ldst = &tiles[w][0];
#pragma unroll
        for (int t = 0; t < 8; ++t)
            gl_lds16(gsrc + (size_t)(16 * t + rr) * EDIM, ldst + t * 512);
        __syncthreads();

        short8 bh[4], bl[4];
#pragma unroll
        for (int ct = 0; ct < 4; ++ct) {
            int r = wc * 64 + ct * 16 + l15;
            bh[ct] = *(const short8*)&tiles[2][r * 32 + q8];
            bl[ct] = *(const short8*)&tiles[3][r * 32 + q8];
        }
#pragma unroll
        for (int rt = 0; rt < 4; ++rt) {
            int r = wr * 64 + rt * 16 + l15;
            short8 ah = *(const short8*)&tiles[0][r * 32 + q8];
            short8 al = *(const short8*)&tiles[1][r * 32 + q8];
#pragma unroll
            for (int ct = 0; ct < 4; ++ct) {
                acc[rt][ct] = __builtin_amdgcn_mfma_f32_16x16x32_bf16(ah, bh[ct], acc[rt][ct], 0, 0, 0);
                acc[rt][ct] = __builtin_amdgcn_mfma_f32_16x16x32_bf16(ah, bl[ct], acc[rt][ct], 0, 0, 0);
                acc[rt][ct] = __builtin_amdgcn_mfma_f32_16x16x32_bf16(al, bh[ct], acc[rt][ct], 0, 0, 0);
            }
        }
        __syncthreads();
    }

#pragma unroll
    for (int rt = 0; rt < 4; ++rt) {
        float m[4];
#pragma unroll
        for (int reg = 0; reg < 4; ++reg) {
            float mm = acc[rt][0][reg];
#pragma unroll
            for (int ct = 1; ct < 4; ++ct) mm = fmaxf(mm, acc[rt][ct][reg]);
            m[reg] = mm;
        }
#pragma unroll
        for (int off = 1; off < 16; off <<= 1)
#pragma unroll
            for (int reg = 0; reg < 4; ++reg) m[reg] = fmaxf(m[reg], __shfl_xor(m[reg], off));
        if (l15 == 0) {
#pragma unroll
            for (int reg = 0; reg < 4; ++reg)
                redbuf[wc * 128 + wr * 64 + rt * 16 + quad * 4 + reg] = m[reg];
        }
    }
    __syncthreads();

    double part = 0.0;
    if (tid < 128) part = (double)fmaxf(redbuf[tid], redbuf[128 + tid]);
#pragma unroll
    for (int off = 1; off < 64; off <<= 1) part += __shfl_xor(part, off);
    if (lane == 0 && w < 2) red2[w] = part;
    __syncthreads();
    if (tid == 0) scores[(b * NCHUNK + i) * NCHUNK + j] = (float)(red2[0] + red2[1]);
}

// ---------------------------------------------------------------------------
// Stage D v5: out = dp @ ext + chunk, single-pass bf16 MFMA, inlined top-k,
// e-tile 64 (2 blocks/CU) — r12 version + the same XOR bank swizzle.
// ---------------------------------------------------------------------------
__global__ __launch_bounds__(256) void out_mfma(const float* __restrict__ x,
                                                const short* __restrict__ dph,
                                                const short* __restrict__ xth,
                                                const float* __restrict__ scores,
                                                float* __restrict__ out) {
    __shared__ short As[2][128 * 32];   // [buf][c][k]  8 KB each
    __shared__ short Bs[2][64 * 32];    // [buf][e][k]  4 KB each
    __shared__ int   slist[8], sslot[8], snum;
    __shared__ float swei[8];

    const int eq = blockIdx.x, n = blockIdx.y, b = blockIdx.z;
    const int e0 = eq * 64;
    const int tid  = threadIdx.x;
    const int w    = tid >> 6, lane = tid & 63;
    const int wr   = w >> 1, wc = w & 1;
    const int quad = lane >> 4, l15 = lane & 15;
    const int rr   = lane >> 2;
    const int c16  = (lane & 3) * 8;
    const int csw  = c16 ^ (((rr >> 1) & 3) * 8);
    const int q8   = (quad ^ ((l15 >> 1) & 3)) * 8;

    // ---- inlined top-7 (wave 0): candidates j in [0, n) ----
    if (w == 0) {
        const float* srow = scores + (b * NCHUNK + n) * NCHUNK;
        const int nsel = n < KSEL ? n : KSEL;
        float v = (lane < n) ? srow[lane] : -3.0e38f;
        float vals[KSEL];
        int   idxs[KSEL];
        for (int s2 = 0; s2 < nsel; ++s2) {
            float bv = v; int bi = lane;
#pragma unroll
            for (int off = 1; off < 64; off <<= 1) {
                float ov = __shfl_xor(bv, off);
                int   oi = __shfl_xor(bi, off);
                if (ov > bv || (ov == bv && oi < bi)) { bv = ov; bi = oi; }
            }
            vals[s2] = bv; idxs[s2] = bi;
            if (lane == bi) v = -3.0e38f;
        }
        if (lane == 0) {
            float vmin = (nsel > 0) ? vals[nsel - 1] : 0.0f;
            float inv  = 1.0f / (vmin + 1e-6f);
            int shift  = KSEL - nsel;
            int c = 0;
            for (int s2 = 0; s2 < 8; ++s2) {
                int jj; float ww;
                if (s2 < KSEL) {
                    int tt = s2 - shift;
                    if (tt >= 0) { jj = idxs[tt]; ww = vals[tt] * inv; }
                    else         { jj = -1;       ww = 0.0f; }
                } else { jj = n; ww = 1.0f; }
                if (jj >= 0) { slist[c] = jj; sslot[c] = s2; swei[c] = ww; ++c; }
            }
            snum = c;
        }
    }
    __syncthreads();
    const int NS = snum * 4;   // flattened steps (kk=0..3 per valid slot)

    auto stage = [&](int st, int bf) {
        int sv = st >> 2, kk = st & 3;
        if (w < 2) {
            const short* gsrc = dph + (size_t)(sslot[sv] * 128 + kk * 32) + csw;
#pragma unroll
            for (int t = 0; t < 4; ++t)
                gl_lds16(gsrc + (size_t)(w * 64 + t * 16 + rr) * LEXT,
                         &As[bf][(w * 64 + t * 16) * 32]);
        } else {
            const short* gsrc = xth + ((size_t)(b * EDIM + e0)) * TLEN
                                + (size_t)(slist[sv] * CS + kk * 32) + csw;
#pragma unroll
            for (int t = 0; t < 2; ++t)
                gl_lds16(gsrc + (size_t)((w - 2) * 32 + t * 16 + rr) * TLEN,
                         &Bs[bf][((w - 2) * 32 + t * 16) * 32]);
        }
    };

    floatx4 accT[4][2], accP[4][2];
#pragma unroll
    for (int rt = 0; rt < 4; ++rt)
#pragma unroll
        for (int ct = 0; ct < 2; ++ct) accT[rt][ct] = (floatx4){0.f, 0.f, 0.f, 0.f};

    stage(0, 0);
    __syncthreads();

    int buf = 0;
    for (int st = 0; st < NS; ++st) {
        if (st + 1 < NS) stage(st + 1, buf ^ 1);

        if ((st & 3) == 0) {
#pragma unroll
            for (int rt = 0; rt < 4; ++rt)
#pragma unroll
                for (int ct = 0; ct < 2; ++ct) accP[rt][ct] = (floatx4){0.f, 0.f, 0.f, 0.f};
        }

        short8 bh[2];
#pragma unroll
        for (int ct = 0; ct < 2; ++ct) {
            int e = wc * 32 + ct * 16 + l15;
            bh[ct] = *(const short8*)&Bs[buf][e * 32 + q8];
        }
#pragma unroll
        for (int rt = 0; rt < 4; ++rt) {
            int r = wr * 64 + rt * 16 + l15;
            short8 ah = *(const short8*)&As[buf][r * 32 + q8];
#pragma unroll
            for (int ct = 0; ct < 2; ++ct)
                accP[rt][ct] = __builtin_amdgcn_mfma_f32_16x16x32_bf16(ah, bh[ct], accP[rt][ct], 0, 0, 0);
        }

        if ((st & 3) == 3) {
            float wcur = swei[st >> 2];
#pragma unroll
            for (int rt = 0; rt < 4; ++rt)
#pragma unroll
                for (int ct = 0; ct < 2; ++ct)
#pragma unroll
                    for (int reg = 0; reg < 4; ++reg)
                        accT[rt][ct][reg] += wcur * accP[rt][ct][reg];
        }
        __syncthreads();
        buf ^= 1;
    }

#pragma unroll
    for (int rt = 0; rt < 4; ++rt)
#pragma unroll
        for (int ct = 0; ct < 2; ++ct) {
#pragma unroll
            for (int reg = 0; reg < 4; ++reg) {
                int row = wr * 64 + rt * 16 + quad * 4 + reg;
                int col = wc * 32 + ct * 16 + l15;
                size_t o = ((size_t)(b * TLEN + n * CS + row)) * EDIM + e0 + col;
                out[o] = accT[rt][ct][reg] + x[o];
            }
        }
}

// ---------------------------------------------------------------------------
extern "C" void kernel_launch(void* const* d_in, const int* in_sizes, int n_in,
                              void* d_out, int out_size, void* d_ws, size_t ws_size,
                              hipStream_t stream) {
    const float* x  = (const float*)d_in[0];   // [2, 8192, 256] fp32
    const float* dp = (const float*)d_in[1];   // [128, 1024] fp32
    float* out = (float*)d_out;

    char* ws = (char*)d_ws;
    short* cn_hi  = (short*)(ws);                       // 8 MB
    short* cn_lo  = (short*)(ws + (8u << 20));          // 8 MB
    short* xt_hi  = (short*)(ws + (16u << 20));         // 8 MB
    short* dp_hi  = (short*)(ws + (24u << 20));         // 256 KB
    float* scores = (float*)(ws + (25u << 20));         // 32 KB

    prep_kernel <<<dim3(264), 256, 0, stream>>>(x, dp, cn_hi, cn_lo, xt_hi, dp_hi);
    scores_mfma <<<dim3(NCHUNK * (NCHUNK - 1) / 2, NBATCH), 256, 0, stream>>>(cn_hi, cn_lo, scores);
    out_mfma    <<<dim3(4, NCHUNK, NBATCH), 256, 0, stream>>>(x, dp_hi, xt_hi, scores, out);
}